// Round 6
// baseline (183.554 us; speedup 1.0000x reference)
//
#include <hip/hip_runtime.h>

// x: [B=64, C=2048, J=8] fp32 ; W: [K=32, C=2048, I=16, J=8] fp32
// out v: [B=64, K=32, I=16] fp32
#define Bn 64
#define Cn 2048
#define Kn 32
#define In 16
#define EPSf 1e-7f

#define NOUT (Bn * Kn * In)   // 32768
#define NCG  128              // iter-2 c-group partials
#define KJ   (Cn * 8)         // 16384 contraction length
#define KSPLIT 32

typedef short bf8v __attribute__((ext_vector_type(8)));
typedef float f4v  __attribute__((ext_vector_type(4)));
typedef float v2f  __attribute__((ext_vector_type(2)));

union U16B { uint4 u; bf8v v; unsigned short h[8]; };

__device__ __forceinline__ unsigned short f2bf(float f) {
    unsigned u = __float_as_uint(f);
    u += 0x7FFF + ((u >> 16) & 1);          // RNE
    return (unsigned short)(u >> 16);
}

__device__ __forceinline__ bf8v cvt8(float4 a, float4 b) {
    U16B o;
    o.h[0] = f2bf(a.x); o.h[1] = f2bf(a.y); o.h[2] = f2bf(a.z); o.h[3] = f2bf(a.w);
    o.h[4] = f2bf(b.x); o.h[5] = f2bf(b.y); o.h[6] = f2bf(b.z); o.h[7] = f2bf(b.w);
    return o.v;
}

// packed-fp32 dot of 8: 1 pk_mul + 3 pk_fma + 1 add
__device__ __forceinline__ float dot8v(float4 wA, float4 wB, float4 xA, float4 xB) {
    union F2 { float4 f; v2f h[2]; };
    F2 ua{wA}, ub{wB}, xa{xA}, xb{xB};
    v2f s = ua.h[0] * xa.h[0];
    s += ua.h[1] * xa.h[1];
    s += ub.h[0] * xb.h[0];
    s += ub.h[1] * xb.h[1];
    return s.x + s.y;
}

// ---------------------------------------------------------------------------
// kGemm1: iter-1 S1 partials via MFMA, streaming W/x fp32 with inline bf16
// conversion (no prep kernels). 256 blocks = 8 nstrips x 32 ksplits, 4 waves
// = 4 m-tiles. B-fragment address map identical to R5's kPrepW (validated):
//   n-tile nt => k_out = nt, i = lane&15, c = ks*4 + (lane>>4), j = 0..7.
// Lanes 0..15 read contiguous 512 B; wave reads 2 KB contiguous per tile.
// ---------------------------------------------------------------------------
__global__ __launch_bounds__(256) void kGemm1(const float* __restrict__ x,
                                              const float* __restrict__ W,
                                              float* __restrict__ part1)
{
    const int nstrip = blockIdx.x & 7;
    const int ksplit = blockIdx.x >> 3;       // 0..31
    const int ks0    = ksplit * (512 / KSPLIT);
    const int lane   = threadIdx.x & 63;
    const int m0     = (threadIdx.x >> 6) * 16;

    f4v acc[4] = {};
    const float* xrow = x + (size_t)(m0 + (lane & 15)) * KJ + (lane >> 4) * 8;

    for (int s = 0; s < 512 / KSPLIT; ++s) {
        const int ks = ks0 + s;
        const float4* xp = (const float4*)(xrow + ks * 32);
        bf8v af = cvt8(xp[0], xp[1]);
        #pragma unroll
        for (int t = 0; t < 4; ++t) {
            const int nt = nstrip * 4 + t;            // == k_out
            const int c  = ks * 4 + (lane >> 4);
            const float4* wp = (const float4*)(W + (((size_t)nt * Cn + c) * 16 + (lane & 15)) * 8);
            bf8v bfr = cvt8(wp[0], wp[1]);
            acc[t] = __builtin_amdgcn_mfma_f32_16x16x32_bf16(af, bfr, acc[t], 0, 0, 0);
        }
    }

    // C/D layout: col = lane&15, row = (lane>>4)*4 + reg
    float* pb = part1 + (size_t)ksplit * NOUT;
    const int col   = lane & 15;
    const int rbase = (lane >> 4) * 4;
    #pragma unroll
    for (int t = 0; t < 4; ++t) {
        const int n = (nstrip * 4 + t) * 16 + col;
        #pragma unroll
        for (int r = 0; r < 4; ++r)
            pb[(size_t)(m0 + rbase + r) * 512 + n] = acc[t][r];
    }
}

// ---------------------------------------------------------------------------
// kSq1: v1 = squash( (1/32) * sum_splits part1 ). 8192 threads, float4 each.
// ---------------------------------------------------------------------------
__global__ __launch_bounds__(256) void kSq1(const float* __restrict__ part1,
                                            float* __restrict__ v1)
{
    const int t = blockIdx.x * 256 + threadIdx.x;   // 0..8191
    const size_t o = (size_t)t * 4;
    float4 s = make_float4(0.f, 0.f, 0.f, 0.f);
    #pragma unroll 8
    for (int g = 0; g < KSPLIT; ++g) {
        const float4 p = *(const float4*)(part1 + (size_t)g * NOUT + o);
        s.x += p.x; s.y += p.y; s.z += p.z; s.w += p.w;
    }
    const float sc = 1.0f / 32.0f;
    s.x *= sc; s.y *= sc; s.z *= sc; s.w *= sc;
    float sq = (s.x * s.x + s.y * s.y) + (s.z * s.z + s.w * s.w);
    sq += __shfl_xor(sq, 1);
    sq += __shfl_xor(sq, 2);
    const float f = (sq / (1.0f + sq)) * rsqrtf(sq + EPSf);
    *(float4*)(v1 + o) = make_float4(s.x * f, s.y * f, s.z * f, s.w * f);
}

// ---------------------------------------------------------------------------
// kC: iter-2 routing partials, recompute structure. BSUB=4 -> 2048 blocks
// (8 blocks/CU reachable; was grid-capped at 4). Packed-fp32 dots.
// tid = k*8+ih; thread owns i = 2ih,2ih+1. XCD swizzle: xcd owns a 16-cg
// band, bg varies fastest so W chunks stay hot in that XCD's L2.
// ---------------------------------------------------------------------------
#define BSUB_C 4
#define CCC    8
#define NCH    2
__global__ __launch_bounds__(256) void kC(const float* __restrict__ x,
                                          const float* __restrict__ W,
                                          const float* __restrict__ v1,
                                          float* __restrict__ part2)
{
    const int xcd = blockIdx.x & 7;
    const int idx = blockIdx.x >> 3;          // 0..255
    const int bg  = idx & 15;                 // fastest: 16 bgroups
    const int cgl = idx >> 4;                 // 0..15
    const int cg  = xcd * 16 + cgl;           // 0..127
    const int k   = threadIdx.x >> 3;
    const int ih  = threadIdx.x & 7;

    __shared__ float e_s[BSUB_C][CCC][33];
    __shared__ float dinv[BSUB_C * CCC];

    float v1r[BSUB_C][2];
    #pragma unroll
    for (int b = 0; b < BSUB_C; ++b) {
        const float2 v = *(const float2*)(v1 + ((size_t)((bg * BSUB_C + b) * Kn + k)) * In + 2 * ih);
        v1r[b][0] = v.x;
        v1r[b][1] = v.y;
    }

    float acc[BSUB_C][2] = {};

    for (int ch = 0; ch < NCH; ++ch) {
        const int c0 = cg * (NCH * CCC) + ch * CCC;

        // ---- pass A: agreements -> exp in LDS ----
        #pragma unroll 2
        for (int cl = 0; cl < CCC; ++cl) {
            const int c = c0 + cl;
            const float4* wp = (const float4*)(W + ((size_t)(k * Cn + c)) * 128 + ih * 16);
            float4 w0 = wp[0], w1 = wp[1], w2 = wp[2], w3 = wp[3];
            #pragma unroll
            for (int b = 0; b < BSUB_C; ++b) {
                const float4* xp = (const float4*)(x + ((size_t)((bg * BSUB_C + b) * Cn + c)) * 8);
                float4 x0 = xp[0], x1 = xp[1];
                float a0 = dot8v(w0, w1, x0, x1);
                float a1 = dot8v(w2, w3, x0, x1);
                float p = a0 * v1r[b][0] + a1 * v1r[b][1];
                p += __shfl_xor(p, 1);
                p += __shfl_xor(p, 2);
                p += __shfl_xor(p, 4);
                if (ih == 0) e_s[b][cl][k] = __expf(p);
            }
        }
        __syncthreads();

        // ---- phase 2: softmax denominators for 32 (b,c) pairs ----
        {
            const int p  = threadIdx.x >> 3;   // 0..31
            const int l  = threadIdx.x & 7;
            const int pb = p >> 3, pc = p & 7;
            const float* ep = &e_s[pb][pc][4 * l];
            float ssum = (ep[0] + ep[1]) + (ep[2] + ep[3]);
            ssum += __shfl_xor(ssum, 1);
            ssum += __shfl_xor(ssum, 2);
            ssum += __shfl_xor(ssum, 4);
            if (l == 0) dinv[p] = 1.0f / ssum;
        }
        __syncthreads();

        // ---- pass B: recompute u from L2-hot W, weighted accumulate ----
        #pragma unroll 2
        for (int cl = 0; cl < CCC; ++cl) {
            const int c = c0 + cl;
            const float4* wp = (const float4*)(W + ((size_t)(k * Cn + c)) * 128 + ih * 16);
            float4 w0 = wp[0], w1 = wp[1], w2 = wp[2], w3 = wp[3];
            #pragma unroll
            for (int b = 0; b < BSUB_C; ++b) {
                const float4* xp = (const float4*)(x + ((size_t)((bg * BSUB_C + b) * Cn + c)) * 8);
                float4 x0 = xp[0], x1 = xp[1];
                float a0 = dot8v(w0, w1, x0, x1);
                float a1 = dot8v(w2, w3, x0, x1);
                const float cc = e_s[b][cl][k] * dinv[b * CCC + cl];
                acc[b][0] += cc * a0;
                acc[b][1] += cc * a1;
            }
        }
        if (ch + 1 < NCH) __syncthreads();
    }

    float* base = part2 + (size_t)cg * NOUT;
    #pragma unroll
    for (int b = 0; b < BSUB_C; ++b) {
        float2 v = { acc[b][0], acc[b][1] };
        *(float2*)(base + ((size_t)(bg * BSUB_C + b) * Kn + k) * In + 2 * ih) = v;
    }
}

// ---------------------------------------------------------------------------
// kRed2: out = squash( sum_cg part2 ). 16384 threads, float2 each.
// ---------------------------------------------------------------------------
__global__ __launch_bounds__(256) void kRed2(const float* __restrict__ part,
                                             float* __restrict__ out)
{
    const int t = blockIdx.x * 256 + threadIdx.x;   // 0..16383
    const size_t o = (size_t)t * 2;
    float2 s = make_float2(0.f, 0.f);
    #pragma unroll 8
    for (int cg = 0; cg < NCG; ++cg) {
        const float2 p = *(const float2*)(part + (size_t)cg * NOUT + o);
        s.x += p.x; s.y += p.y;
    }
    float sq = s.x * s.x + s.y * s.y;
    sq += __shfl_xor(sq, 1);
    sq += __shfl_xor(sq, 2);
    sq += __shfl_xor(sq, 4);
    const float f = (sq / (1.0f + sq)) * rsqrtf(sq + EPSf);
    *(float2*)(out + o) = make_float2(s.x * f, s.y * f);
}

extern "C" void kernel_launch(void* const* d_in, const int* in_sizes, int n_in,
                              void* d_out, int out_size, void* d_ws, size_t ws_size,
                              hipStream_t stream)
{
    const float* x = (const float*)d_in[0];   // [64,2048,8]
    const float* W = (const float*)d_in[1];   // [32,2048,16,8]
    float* out = (float*)d_out;               // [64,32,16]

    float* wsf = (float*)d_ws;
    float* part1 = wsf;                                   // 4 MiB (32 x 32768)
    float* v1    = wsf + (size_t)KSPLIT * NOUT;           // 128 KiB
    float* part2 = wsf + (size_t)KSPLIT * NOUT + NOUT;    // 16 MiB (128 x 32768)

    kGemm1<<<256,  256, 0, stream>>>(x, W, part1);
    kSq1  <<<32,   256, 0, stream>>>(part1, v1);
    kC    <<<2048, 256, 0, stream>>>(x, W, v1, part2);
    kRed2 <<<64,   256, 0, stream>>>(part2, out);
}

// Round 7
// 180.227 us; speedup vs baseline: 1.0185x; 1.0185x over previous
//
#include <hip/hip_runtime.h>

// x: [B=64, C=2048, J=8] fp32 ; W: [K=32, C=2048, I=16, J=8] fp32
// out v: [B=64, K=32, I=16] fp32
#define Bn 64
#define Cn 2048
#define Kn 32
#define In 16
#define EPSf 1e-7f

#define NOUT (Bn * Kn * In)   // 32768
#define KJ   (Cn * 8)         // 16384 contraction length
#define KSPLIT1 32            // iter-1 GEMM split-K
#define KSPLIT2 16            // iter-2 GEMM split-K

typedef short bf8v __attribute__((ext_vector_type(8)));
typedef float f4v  __attribute__((ext_vector_type(4)));
typedef float v2f  __attribute__((ext_vector_type(2)));

union U16B { uint4 u; bf8v v; unsigned short h[8]; };

__device__ __forceinline__ unsigned short f2bf(float f) {
    unsigned u = __float_as_uint(f);
    u += 0x7FFF + ((u >> 16) & 1);          // RNE
    return (unsigned short)(u >> 16);
}

__device__ __forceinline__ bf8v cvt8(float4 a, float4 b) {
    U16B o;
    o.h[0] = f2bf(a.x); o.h[1] = f2bf(a.y); o.h[2] = f2bf(a.z); o.h[3] = f2bf(a.w);
    o.h[4] = f2bf(b.x); o.h[5] = f2bf(b.y); o.h[6] = f2bf(b.z); o.h[7] = f2bf(b.w);
    return o.v;
}

// packed-fp32 dot of 8
__device__ __forceinline__ float dot8v(float4 wA, float4 wB, float4 xA, float4 xB) {
    union F2 { float4 f; v2f h[2]; };
    F2 ua{wA}, ub{wB}, xa{xA}, xb{xB};
    v2f s = ua.h[0] * xa.h[0];
    s += ua.h[1] * xa.h[1];
    s += ub.h[0] * xb.h[0];
    s += ub.h[1] * xb.h[1];
    return s.x + s.y;
}

// ---------------------------------------------------------------------------
// kGemm1: iter-1 S1 partials via MFMA, inline bf16 convert (validated R5/R6).
// 256 blocks = 8 nstrips x 32 ksplits, 4 waves = 4 m-tiles (all of B).
// B-frag map: n-tile nt == k_out; i = lane&15; c = ks*4 + (lane>>4); j = 0..7.
// ---------------------------------------------------------------------------
__global__ __launch_bounds__(256) void kGemm1(const float* __restrict__ x,
                                              const float* __restrict__ W,
                                              float* __restrict__ part1)
{
    const int nstrip = blockIdx.x & 7;
    const int ksplit = blockIdx.x >> 3;
    const int ks0    = ksplit * (512 / KSPLIT1);
    const int lane   = threadIdx.x & 63;
    const int m0     = (threadIdx.x >> 6) * 16;

    f4v acc[4] = {};
    const float* xrow = x + (size_t)(m0 + (lane & 15)) * KJ + (lane >> 4) * 8;

    for (int s = 0; s < 512 / KSPLIT1; ++s) {
        const int ks = ks0 + s;
        const float4* xp = (const float4*)(xrow + ks * 32);
        bf8v af = cvt8(xp[0], xp[1]);
        #pragma unroll
        for (int t = 0; t < 4; ++t) {
            const int nt = nstrip * 4 + t;            // == k_out
            const int c  = ks * 4 + (lane >> 4);
            const float4* wp = (const float4*)(W + (((size_t)nt * Cn + c) * 16 + (lane & 15)) * 8);
            bf8v bfr = cvt8(wp[0], wp[1]);
            acc[t] = __builtin_amdgcn_mfma_f32_16x16x32_bf16(af, bfr, acc[t], 0, 0, 0);
        }
    }

    float* pb = part1 + (size_t)ksplit * NOUT;
    const int col   = lane & 15;
    const int rbase = (lane >> 4) * 4;
    #pragma unroll
    for (int t = 0; t < 4; ++t) {
        const int n = (nstrip * 4 + t) * 16 + col;
        #pragma unroll
        for (int r = 0; r < 4; ++r)
            pb[(size_t)(m0 + rbase + r) * 512 + n] = acc[t][r];
    }
}

// ---------------------------------------------------------------------------
// kSq: out[o] = squash_over_i( scale * sum_{g<nparts} part[g][o] )
// 8192 threads, float4 each; i-norm via 2 xor-shuffles (4-lane groups).
// ---------------------------------------------------------------------------
__global__ __launch_bounds__(256) void kSq(const float* __restrict__ part,
                                           float* __restrict__ out,
                                           float scale, int nparts)
{
    const int t = blockIdx.x * 256 + threadIdx.x;   // 0..8191
    const size_t o = (size_t)t * 4;
    float4 s = make_float4(0.f, 0.f, 0.f, 0.f);
    for (int g = 0; g < nparts; ++g) {
        const float4 p = *(const float4*)(part + (size_t)g * NOUT + o);
        s.x += p.x; s.y += p.y; s.z += p.z; s.w += p.w;
    }
    s.x *= scale; s.y *= scale; s.z *= scale; s.w *= scale;
    float sq = (s.x * s.x + s.y * s.y) + (s.z * s.z + s.w * s.w);
    sq += __shfl_xor(sq, 1);
    sq += __shfl_xor(sq, 2);
    const float f = (sq / (1.0f + sq)) * rsqrtf(sq + EPSf);
    *(float4*)(out + o) = make_float4(s.x * f, s.y * f, s.z * f, s.w * f);
}

// ---------------------------------------------------------------------------
// kAgrCC: agreements + softmax only (no pass B, no u storage, no recompute).
// tid = k*8+ih; thread computes agr-partial for i = 2ih,2ih+1; BSUB=4 b per
// block share W loads. Writes cc[k][c][b] for kGemm2's coalesced A reads.
// XCD swizzle: xcd owns a 16-cg band; bg fastest. 2048 blocks.
// ---------------------------------------------------------------------------
#define BSUB 4
#define CCC  8
#define NCH  2
__global__ __launch_bounds__(256) void kAgrCC(const float* __restrict__ x,
                                              const float* __restrict__ W,
                                              const float* __restrict__ v1,
                                              float* __restrict__ cc)
{
    const int xcd = blockIdx.x & 7;
    const int idx = blockIdx.x >> 3;          // 0..255
    const int bg  = idx & 15;                 // fastest: 16 bgroups
    const int cgl = idx >> 4;                 // 0..15
    const int cg  = xcd * 16 + cgl;           // 0..127
    const int k   = threadIdx.x >> 3;
    const int ih  = threadIdx.x & 7;

    __shared__ float e_s[BSUB][CCC][33];
    __shared__ float dinv[BSUB * CCC];

    float v1r[BSUB][2];
    #pragma unroll
    for (int b = 0; b < BSUB; ++b) {
        const float2 v = *(const float2*)(v1 + ((size_t)((bg * BSUB + b) * Kn + k)) * In + 2 * ih);
        v1r[b][0] = v.x;
        v1r[b][1] = v.y;
    }

    for (int ch = 0; ch < NCH; ++ch) {
        const int c0 = cg * (NCH * CCC) + ch * CCC;

        // ---- agreements -> exp in LDS ----
        #pragma unroll 2
        for (int cl = 0; cl < CCC; ++cl) {
            const int c = c0 + cl;
            const float4* wp = (const float4*)(W + ((size_t)(k * Cn + c)) * 128 + ih * 16);
            float4 w0 = wp[0], w1 = wp[1], w2 = wp[2], w3 = wp[3];
            #pragma unroll
            for (int b = 0; b < BSUB; ++b) {
                const float4* xp = (const float4*)(x + ((size_t)((bg * BSUB + b) * Cn + c)) * 8);
                float4 x0 = xp[0], x1 = xp[1];
                float a0 = dot8v(w0, w1, x0, x1);
                float a1 = dot8v(w2, w3, x0, x1);
                float p = a0 * v1r[b][0] + a1 * v1r[b][1];
                p += __shfl_xor(p, 1);
                p += __shfl_xor(p, 2);
                p += __shfl_xor(p, 4);
                if (ih == 0) e_s[b][cl][k] = __expf(p);
            }
        }
        __syncthreads();

        // ---- softmax denominators for 32 (b,c) pairs ----
        {
            const int p  = threadIdx.x >> 3;   // 0..31
            const int l  = threadIdx.x & 7;
            const int pb = p >> 3, pc = p & 7;
            const float* ep = &e_s[pb][pc][4 * l];
            float ssum = (ep[0] + ep[1]) + (ep[2] + ep[3]);
            ssum += __shfl_xor(ssum, 1);
            ssum += __shfl_xor(ssum, 2);
            ssum += __shfl_xor(ssum, 4);
            if (l == 0) dinv[p] = 1.0f / ssum;
        }
        __syncthreads();

        // ---- write cc[k][c][b]: thread handles cl = ih, its k, all b ----
        {
            const int c = c0 + ih;
            #pragma unroll
            for (int b = 0; b < BSUB; ++b)
                cc[((size_t)k * Cn + c) * Bn + bg * BSUB + b] = e_s[b][ih][k] * dinv[b * CCC + ih];
        }
        __syncthreads();   // e_s overwritten next chunk
    }
}

// ---------------------------------------------------------------------------
// kGemm2: s2 partials via MFMA with cc folded into A.
//   s2[b,kk,i] = sum_{c,j} (cc[b,kk,c]*x[b,c,j]) * W[kk,(c,j),i]
// grid 512 = 32 kk x 16 ksplits; 4 waves = 4 m-tiles of 16 b.
// A: b = m0+(lane&15), c = kstep*4+(lane>>4), a = bf16(cc*x[j=0..7]).
// B: identical address map to kGemm1 with nt = kk (validated).
// ---------------------------------------------------------------------------
__global__ __launch_bounds__(256) void kGemm2(const float* __restrict__ x,
                                              const float* __restrict__ W,
                                              const float* __restrict__ cc,
                                              float* __restrict__ part2)
{
    const int kk  = blockIdx.x & 31;
    const int ksp = blockIdx.x >> 5;          // 0..15
    const int lane = threadIdx.x & 63;
    const int m0   = (threadIdx.x >> 6) * 16;
    const int b    = m0 + (lane & 15);

    f4v acc = {};

    for (int s = 0; s < 32; ++s) {
        const int kstep = ksp * 32 + s;
        const int c = kstep * 4 + (lane >> 4);
        const float ccv = cc[((size_t)kk * Cn + c) * Bn + b];
        const float4* xp = (const float4*)(x + ((size_t)b * Cn + c) * 8);
        float4 x0 = xp[0], x1 = xp[1];
        x0.x *= ccv; x0.y *= ccv; x0.z *= ccv; x0.w *= ccv;
        x1.x *= ccv; x1.y *= ccv; x1.z *= ccv; x1.w *= ccv;
        bf8v af = cvt8(x0, x1);
        const float4* wp = (const float4*)(W + (((size_t)kk * Cn + c) * 16 + (lane & 15)) * 8);
        bf8v bfr = cvt8(wp[0], wp[1]);
        acc = __builtin_amdgcn_mfma_f32_16x16x32_bf16(af, bfr, acc, 0, 0, 0);
    }

    // C/D: col = lane&15 = i, row = b = m0 + (lane>>4)*4 + r
    float* pb = part2 + (size_t)ksp * NOUT;
    const int i     = lane & 15;
    const int rbase = m0 + (lane >> 4) * 4;
    #pragma unroll
    for (int r = 0; r < 4; ++r)
        pb[((size_t)(rbase + r) * Kn + kk) * In + i] = acc[r];
}

extern "C" void kernel_launch(void* const* d_in, const int* in_sizes, int n_in,
                              void* d_out, int out_size, void* d_ws, size_t ws_size,
                              hipStream_t stream)
{
    const float* x = (const float*)d_in[0];   // [64,2048,8]
    const float* W = (const float*)d_in[1];   // [32,2048,16,8]
    float* out = (float*)d_out;               // [64,32,16]

    float* wsf = (float*)d_ws;
    float* part1 = wsf;                                        // 4 MiB
    float* v1    = part1 + (size_t)KSPLIT1 * NOUT;             // 128 KiB
    float* cc    = v1 + NOUT;                                  // 16.8 MiB (32*2048*64)
    float* part2 = cc + (size_t)Kn * Cn * Bn;                  // 2 MiB

    kGemm1<<<256,  256, 0, stream>>>(x, W, part1);
    kSq   <<<32,   256, 0, stream>>>(part1, v1, 1.0f / 32.0f, KSPLIT1);
    kAgrCC<<<2048, 256, 0, stream>>>(x, W, v1, cc);
    kGemm2<<<512,  256, 0, stream>>>(x, W, cc, part2);
    kSq   <<<32,   256, 0, stream>>>(part2, out, 1.0f, KSPLIT2);
}